// Round 7
// baseline (416.786 us; speedup 1.0000x reference)
//
#include <hip/hip_runtime.h>
#include <hip/hip_cooperative_groups.h>
#include <hip/hip_bf16.h>
#include <cstddef>

namespace cg = cooperative_groups;

#define T_TOK 1024
#define D_DIM 1024
#define H_DIM 512
#define E_EXP 8
#define P_CAP 2560          // max padded pairs: 2048 + 8*63 = 2552 -> 2560
#define LDA 72              // shorts per LDS row: 64 data + 8 pad (144B, 16B-aligned)

typedef __attribute__((ext_vector_type(4))) float    float4_t;
typedef __attribute__((ext_vector_type(8))) short    short8_t;
typedef __attribute__((ext_vector_type(4))) unsigned uint4_t;

__device__ __forceinline__ short f2bf(float f) {
  union { float f; unsigned u; } v; v.f = f;
  unsigned u = v.u;
  u += 0x7FFFu + ((u >> 16) & 1u);
  return (short)(u >> 16);
}

// packed fp32x2 -> bf16x2; low short = a, high = b
__device__ __forceinline__ unsigned pkbf(float a, float b) {
  union { __hip_bfloat162 h; unsigned u; } v;
  v.h = __float22bfloat162_rn(make_float2(a, b));
  return v.u;
}

__global__ __launch_bounds__(256, 2) void fused_kernel(
    const float* __restrict__ w1, const float* __restrict__ w3,
    const float* __restrict__ w2, const float* __restrict__ x,
    const float* __restrict__ gw, short* __restrict__ w13t,
    short* __restrict__ w2t, int* __restrict__ idx2,
    float* __restrict__ scale2, int* __restrict__ pair_tok,
    float* __restrict__ pair_scale, int* __restrict__ meta,
    short* __restrict__ h, float* __restrict__ out) {
  cg::grid_group grid = cg::this_grid();
  __shared__ __align__(16) char smem[18432];
  const int bid = blockIdx.x;
  const int nb  = gridDim.x;
  const int tid = threadIdx.x;
  const int lane = tid & 63, wid = tid >> 6;

  // ================= Phase A: weight conv + router + out zero =============
  // jobs 0..3071: wconv (24 planes x 128 tiles); 3072..3327: router;
  // 3328..3583: zero out[] (256 x 16KB chunks)
  for (int j = bid; j < 3584; j += nb) {
    if (j < 3072) {
      float (*tile)[68] = (float(*)[68])smem;
      int z = j >> 7, sub = j & 127;
      const float* src; short* dst; int N, ldd, row_off, xt, yt;
      if (z < 16) {
        int which = z >> 3, e = z & 7;
        src = (which ? w3 : w1) + (size_t)e * D_DIM * H_DIM;
        dst = w13t + (size_t)e * D_DIM * (2 * H_DIM);
        N = H_DIM; ldd = D_DIM; row_off = which ? H_DIM : 0;
        xt = sub >> 3; yt = sub & 7;       // 16 k-tiles x 8 n-tiles
      } else {
        int e = z - 16;
        src = w2 + (size_t)e * H_DIM * D_DIM;
        dst = w2t + (size_t)e * D_DIM * H_DIM;
        N = D_DIM; ldd = H_DIM; row_off = 0;
        xt = sub & 7; yt = sub >> 3;       // 8 k-tiles x 16 n-tiles
      }
      const int k0 = xt * 64, n0 = yt * 64;
      const int kr = tid >> 4, nc = (tid & 15) * 4;
      #pragma unroll
      for (int p = 0; p < 4; ++p) {
        int k = p * 16 + kr;
        float4_t v = *(const float4_t*)(src + (size_t)(k0 + k) * N + n0 + nc);
        *(float4_t*)&tile[k][nc] = v;
      }
      __syncthreads();
      const int r8 = tid >> 3, c8 = tid & 7;
      #pragma unroll
      for (int p = 0; p < 2; ++p) {
        int row = p * 32 + r8;
        uint4_t u;
        #pragma unroll
        for (int jj = 0; jj < 4; ++jj)
          u[jj] = pkbf(tile[c8 * 8 + 2 * jj][row], tile[c8 * 8 + 2 * jj + 1][row]);
        *(uint4_t*)(dst + (size_t)(row_off + n0 + row) * ldd + k0 + c8 * 8) = u;
      }
      __syncthreads();   // protect tile before next job's load
    } else if (j < 3328) {
      // router: 4 tokens, one per wave
      const int t = (j - 3072) * 4 + wid;
      const float* xr = x + (size_t)t * D_DIM;
      float acc[E_EXP];
      #pragma unroll
      for (int e = 0; e < E_EXP; ++e) acc[e] = 0.f;
      for (int d = lane; d < D_DIM; d += 64) {
        float xv = xr[d];
        float4_t g0 = *(const float4_t*)(gw + d * E_EXP);
        float4_t g1 = *(const float4_t*)(gw + d * E_EXP + 4);
        acc[0] += xv * g0[0]; acc[1] += xv * g0[1];
        acc[2] += xv * g0[2]; acc[3] += xv * g0[3];
        acc[4] += xv * g1[0]; acc[5] += xv * g1[1];
        acc[6] += xv * g1[2]; acc[7] += xv * g1[3];
      }
      #pragma unroll
      for (int off = 32; off >= 1; off >>= 1) {
        #pragma unroll
        for (int e = 0; e < E_EXP; ++e) acc[e] += __shfl_down(acc[e], off, 64);
      }
      if (lane == 0) {
        float m = acc[0];
        #pragma unroll
        for (int e = 1; e < E_EXP; ++e) m = fmaxf(m, acc[e]);
        float p[E_EXP]; float s = 0.f;
        #pragma unroll
        for (int e = 0; e < E_EXP; ++e) { p[e] = __expf(acc[e] - m); s += p[e]; }
        float inv = 1.f / s;
        #pragma unroll
        for (int e = 0; e < E_EXP; ++e) p[e] *= inv;
        int i1 = 0;
        #pragma unroll
        for (int e = 1; e < E_EXP; ++e) if (p[e] > p[i1]) i1 = e; // jax low-idx tiebreak
        int i2 = (i1 == 0) ? 1 : 0;
        #pragma unroll
        for (int e = 0; e < E_EXP; ++e) {
          if (e == i1 || e == i2) continue;
          if (p[e] > p[i2]) i2 = e;
        }
        idx2[2 * t]     = i1;  scale2[2 * t]     = p[i1];
        idx2[2 * t + 1] = i2;  scale2[2 * t + 1] = p[i2];
      }
    } else {
      // zero out[]: 16KB chunk
      float4_t z4 = {0.f, 0.f, 0.f, 0.f};
      float4_t* o = (float4_t*)(out + (size_t)(j - 3328) * 4096);
      #pragma unroll
      for (int i = 0; i < 4; ++i) o[i * 256 + tid] = z4;
    }
  }
  grid.sync();

  // ================= Phase B: scan/assign on block 0 ======================
  if (bid == 0) {
    __shared__ int cnt[E_EXP], base[E_EXP], cur[E_EXP];
    if (tid < E_EXP) { cnt[tid] = 0; cur[tid] = 0; }
    for (int p = tid; p < P_CAP; p += 256) { pair_tok[p] = -1; pair_scale[p] = 0.f; }
    __syncthreads();
    for (int t = tid; t < T_TOK; t += 256) {
      atomicAdd(&cnt[idx2[2 * t]], 1);
      atomicAdd(&cnt[idx2[2 * t + 1]], 1);
    }
    __syncthreads();
    if (tid == 0) {
      int b = 0, g = 0;
      for (int e = 0; e < E_EXP; ++e) {
        base[e] = b;
        int al = (cnt[e] + 63) & ~63;
        for (int jj = 0; jj < al; jj += 64) { meta[1 + g] = e; meta[41 + g] = b + jj; ++g; }
        b += al;
      }
      meta[0] = g;  // n_mtiles
    }
    __syncthreads();
    for (int t = tid; t < T_TOK; t += 256) {
      #pragma unroll
      for (int s = 0; s < 2; ++s) {
        int e = idx2[2 * t + s];
        int p = base[e] + atomicAdd(&cur[e], 1);
        pair_tok[p] = t;
        pair_scale[p] = scale2[2 * t + s];
      }
    }
  }
  grid.sync();

  const int n_mt = meta[0];
  const int wr = (tid >> 6) >> 1, wc = (tid >> 6) & 1;
  const int q = lane >> 4, ln = lane & 15;

  // ================= Phase C: gemm1 (64m x 32n tiles) =====================
  // h[p][H] = silu((s*x)@w1e) * ((s*x)@w3e)
  for (int job = bid; job < 16 * n_mt; job += nb) {
    short* As  = (short*)smem;          // 64*LDA
    short* B1s = As + 64 * LDA;         // 32*LDA
    short* B3s = B1s + 32 * LDA;        // 32*LDA
    const int mt   = job >> 4;
    const int e    = meta[1 + mt];
    const int row0 = meta[41 + mt];
    const int n0   = (job & 15) * 32;
    const short* bsrc = w13t + (size_t)e * D_DIM * (2 * H_DIM);

    const int ar = tid >> 2, ak = (tid & 3) * 16;
    const int   tokr = pair_tok[row0 + ar];
    const float sc   = pair_scale[row0 + ar];   // 0 for pad rows -> zeros
    const float* xrow = x + (size_t)(tokr < 0 ? 0 : tokr) * D_DIM + ak;
    const int br = tid >> 3, bu = (tid & 7) * 8;
    const short* b1p = bsrc + (size_t)(n0 + br) * D_DIM + bu;
    const short* b3p = bsrc + (size_t)(H_DIM + n0 + br) * D_DIM + bu;

    float4_t acc1[2], acc3[2];
    acc1[0] = acc1[1] = acc3[0] = acc3[1] = (float4_t){0.f, 0.f, 0.f, 0.f};

    for (int k0 = 0; k0 < D_DIM; k0 += 64) {
      float4_t v0 = *(const float4_t*)(xrow + k0);
      float4_t v1 = *(const float4_t*)(xrow + k0 + 4);
      float4_t v2 = *(const float4_t*)(xrow + k0 + 8);
      float4_t v3 = *(const float4_t*)(xrow + k0 + 12);
      uint4_t vb1 = *(const uint4_t*)(b1p + k0);
      uint4_t vb3 = *(const uint4_t*)(b3p + k0);
      uint4_t u0 = {pkbf(v0[0] * sc, v0[1] * sc), pkbf(v0[2] * sc, v0[3] * sc),
                    pkbf(v1[0] * sc, v1[1] * sc), pkbf(v1[2] * sc, v1[3] * sc)};
      uint4_t u1 = {pkbf(v2[0] * sc, v2[1] * sc), pkbf(v2[2] * sc, v2[3] * sc),
                    pkbf(v3[0] * sc, v3[1] * sc), pkbf(v3[2] * sc, v3[3] * sc)};
      *(uint4_t*)&As[ar * LDA + ak]     = u0;
      *(uint4_t*)&As[ar * LDA + ak + 8] = u1;
      *(uint4_t*)&B1s[br * LDA + bu] = vb1;
      *(uint4_t*)&B3s[br * LDA + bu] = vb3;
      __syncthreads();

      short8_t af[2][2], b1f[2], b3f[2];
      #pragma unroll
      for (int i = 0; i < 2; ++i)
        #pragma unroll
        for (int kk = 0; kk < 2; ++kk)
          af[i][kk] = *(const short8_t*)&As[(wr * 32 + i * 16 + ln) * LDA + kk * 32 + q * 8];
      #pragma unroll
      for (int kk = 0; kk < 2; ++kk) {
        b1f[kk] = *(const short8_t*)&B1s[(wc * 16 + ln) * LDA + kk * 32 + q * 8];
        b3f[kk] = *(const short8_t*)&B3s[(wc * 16 + ln) * LDA + kk * 32 + q * 8];
      }
      #pragma unroll
      for (int i = 0; i < 2; ++i)
        #pragma unroll
        for (int kk = 0; kk < 2; ++kk) {
          acc1[i] = __builtin_amdgcn_mfma_f32_16x16x32_bf16(af[i][kk], b1f[kk], acc1[i], 0, 0, 0);
          acc3[i] = __builtin_amdgcn_mfma_f32_16x16x32_bf16(af[i][kk], b3f[kk], acc3[i], 0, 0, 0);
        }
      __syncthreads();
    }

    #pragma unroll
    for (int i = 0; i < 2; ++i) {
      int r_base = row0 + wr * 32 + i * 16 + q * 4;
      int col = n0 + wc * 16 + ln;
      #pragma unroll
      for (int rr = 0; rr < 4; ++rr) {
        float c1 = acc1[i][rr];
        float c3 = acc3[i][rr];
        float sig = 1.f / (1.f + __expf(-c1));
        h[(size_t)(r_base + rr) * H_DIM + col] = f2bf(c1 * sig * c3);
      }
    }
  }
  grid.sync();

  // ================= Phase D: gemm2 + fused combine (64x64) ===============
  // out[tok] += h[p][H] @ w2t[e]
  for (int job = bid; job < 16 * n_mt; job += nb) {
    short* As = (short*)smem;           // 64*LDA
    short* Bs = As + 64 * LDA;          // 64*LDA
    const int mt   = job >> 4;
    const int e    = meta[1 + mt];
    const int row0 = meta[41 + mt];
    const int n0   = (job & 15) * 64;
    const short* bsrc = w2t + (size_t)e * D_DIM * H_DIM;  // [1024 n][512 k]

    const int ar = tid >> 2, ak = (tid & 3) * 16;
    const short* arow = h + (size_t)(row0 + ar) * H_DIM + ak;
    const short* brow = bsrc + (size_t)(n0 + ar) * H_DIM + ak;

    float4_t acc[2][2];
    #pragma unroll
    for (int i = 0; i < 2; ++i)
      #pragma unroll
      for (int jj = 0; jj < 2; ++jj) acc[i][jj] = (float4_t){0.f, 0.f, 0.f, 0.f};

    for (int k0 = 0; k0 < H_DIM; k0 += 64) {
      uint4_t va0 = *(const uint4_t*)(arow + k0);
      uint4_t va1 = *(const uint4_t*)(arow + k0 + 8);
      uint4_t vb0 = *(const uint4_t*)(brow + k0);
      uint4_t vb1 = *(const uint4_t*)(brow + k0 + 8);
      *(uint4_t*)&As[ar * LDA + ak]     = va0;
      *(uint4_t*)&As[ar * LDA + ak + 8] = va1;
      *(uint4_t*)&Bs[ar * LDA + ak]     = vb0;
      *(uint4_t*)&Bs[ar * LDA + ak + 8] = vb1;
      __syncthreads();

      short8_t af[2][2], bf[2][2];
      #pragma unroll
      for (int i = 0; i < 2; ++i)
        #pragma unroll
        for (int kk = 0; kk < 2; ++kk) {
          af[i][kk] = *(const short8_t*)&As[(wr * 32 + i * 16 + ln) * LDA + kk * 32 + q * 8];
          bf[i][kk] = *(const short8_t*)&Bs[(wc * 32 + i * 16 + ln) * LDA + kk * 32 + q * 8];
        }
      #pragma unroll
      for (int i = 0; i < 2; ++i)
        #pragma unroll
        for (int jj = 0; jj < 2; ++jj)
          #pragma unroll
          for (int kk = 0; kk < 2; ++kk)
            acc[i][jj] = __builtin_amdgcn_mfma_f32_16x16x32_bf16(af[i][kk], bf[jj][kk], acc[i][jj], 0, 0, 0);
      __syncthreads();
    }

    #pragma unroll
    for (int i = 0; i < 2; ++i) {
      int r_base = row0 + wr * 32 + i * 16 + q * 4;
      #pragma unroll
      for (int rr = 0; rr < 4; ++rr) {
        int tok = pair_tok[r_base + rr];
        if (tok < 0) continue;
        float* orow = out + (size_t)tok * D_DIM;
        #pragma unroll
        for (int jj = 0; jj < 2; ++jj) {
          int col = n0 + wc * 32 + jj * 16 + ln;
          atomicAdd(orow + col, acc[i][jj][rr]);
        }
      }
    }
  }
}

extern "C" void kernel_launch(void* const* d_in, const int* in_sizes, int n_in,
                              void* d_out, int out_size, void* d_ws, size_t ws_size,
                              hipStream_t stream) {
  const float* x  = (const float*)d_in[0];   // [2,512,1024]
  const float* gw = (const float*)d_in[1];   // [1024,8]
  const float* w1 = (const float*)d_in[2];   // [8,1024,512] gate
  const float* w3 = (const float*)d_in[4];   // [8,1024,512] up
  const float* w2 = (const float*)d_in[3];   // [8,512,1024] down
  float* out = (float*)d_out;

  char* ws = (char*)d_ws;
  int*   idx2    = (int*)  (ws);                       // 8KB
  float* scale2  = (float*)(ws + 8192);                // 8KB
  int*   ptok    = (int*)  (ws + 16384);               // 10KB (16KB slot)
  float* pscale  = (float*)(ws + 32768);               // 10KB (16KB slot)
  int*   meta    = (int*)  (ws + 49152);               // 512B (16KB slot)
  short* h       = (short*)(ws + (1u << 20));          // 2.62 MB
  short* w13t    = (short*)(ws + (4u << 20));          // 16.8 MB
  short* w2t     = (short*)(ws + (21u << 20));         // 8.4 MB

  // Size the cooperative grid from ACTUAL occupancy (round-6 failure mode:
  // hard-coded 1024 blocks exceeded co-resident capacity -> silent launch err).
  int maxb = 0;
  if (hipOccupancyMaxActiveBlocksPerMultiprocessor(
          &maxb, (const void*)fused_kernel, 256, 0) != hipSuccess || maxb < 1)
    maxb = 1;
  int grid = maxb * 256;          // 256 CUs on MI355X
  if (grid > 1024) grid = 1024;

  void* kargs[] = {&w1, &w3, &w2, &x, &gw, &w13t, &w2t, &idx2, &scale2,
                   &ptok, &pscale, &meta, &h, &out};
  hipLaunchCooperativeKernel((const void*)fused_kernel, dim3(grid), dim3(256),
                             kargs, 0, stream);
}

// Round 8
// 165.942 us; speedup vs baseline: 2.5116x; 2.5116x over previous
//
#include <hip/hip_runtime.h>
#include <hip/hip_bf16.h>
#include <cstddef>

#define T_TOK 1024
#define D_DIM 1024
#define H_DIM 512
#define E_EXP 8
#define MAX_MT 40           // max m-tiles: 8 experts, <=2048+pad rows
#define LDA 72              // shorts per LDS row: 64 data + 8 pad (144B, 16B-aligned)

typedef __attribute__((ext_vector_type(4))) float    float4_t;
typedef __attribute__((ext_vector_type(8))) short    short8_t;
typedef __attribute__((ext_vector_type(4))) unsigned uint4_t;

__device__ __forceinline__ short f2bf(float f) {
  union { float f; unsigned u; } v; v.f = f;
  unsigned u = v.u;
  u += 0x7FFFu + ((u >> 16) & 1u);
  return (short)(u >> 16);
}

// packed fp32x2 -> bf16x2; low short = a, high = b
__device__ __forceinline__ unsigned pkbf(float a, float b) {
  union { __hip_bfloat162 h; unsigned u; } v;
  v.h = __float22bfloat162_rn(make_float2(a, b));
  return v.u;
}

// ---- prep: weight transpose+convert (z<24) + router (z==24) + out=0 (z==25)
// tile stride 69 floats (odd): transpose reads are <=2-way (bank-conflict fix;
// r7 PMC showed 4.5M conflicts, traced to the old stride-68 8-way pattern).
__global__ __launch_bounds__(256) void prep_kernel(
    const float* __restrict__ w1, const float* __restrict__ w3,
    const float* __restrict__ w2, const float* __restrict__ x,
    const float* __restrict__ gw, short* __restrict__ w13t,
    short* __restrict__ w2t, int* __restrict__ idx2,
    float* __restrict__ scale2, float* __restrict__ out) {
  __shared__ float tile[64][69];
  const int z = blockIdx.z;
  const int tid = threadIdx.x;

  if (z < 24) {
    const float* src; short* dst; int N, ldd, row_off;
    if (z < 16) {
      if (blockIdx.y >= 8) return;          // N=512 -> 8 n-tiles
      int which = z >> 3, e = z & 7;
      src = (which ? w3 : w1) + (size_t)e * D_DIM * H_DIM;
      dst = w13t + (size_t)e * D_DIM * (2 * H_DIM);
      N = H_DIM; ldd = D_DIM; row_off = which ? H_DIM : 0;
    } else {
      if (blockIdx.x >= 8) return;          // K=512 -> 8 k-tiles
      int e = z - 16;
      src = w2 + (size_t)e * H_DIM * D_DIM;
      dst = w2t + (size_t)e * D_DIM * H_DIM;
      N = D_DIM; ldd = H_DIM; row_off = 0;
    }
    const int k0 = blockIdx.x * 64, n0 = blockIdx.y * 64;
    const int kr = tid >> 4, nc = (tid & 15) * 4;
    #pragma unroll
    for (int p = 0; p < 4; ++p) {
      int k = p * 16 + kr;
      float4_t v = *(const float4_t*)(src + (size_t)(k0 + k) * N + n0 + nc);
      tile[k][nc]     = v[0];
      tile[k][nc + 1] = v[1];
      tile[k][nc + 2] = v[2];
      tile[k][nc + 3] = v[3];
    }
    __syncthreads();
    const int r8 = tid >> 3, c8 = tid & 7;
    #pragma unroll
    for (int p = 0; p < 2; ++p) {
      int row = p * 32 + r8;
      uint4_t u;
      #pragma unroll
      for (int jj = 0; jj < 4; ++jj)
        u[jj] = pkbf(tile[c8 * 8 + 2 * jj][row], tile[c8 * 8 + 2 * jj + 1][row]);
      *(uint4_t*)(dst + (size_t)(row_off + n0 + row) * ldd + k0 + c8 * 8) = u;
    }
    return;
  }

  if (z == 25) {                            // zero out[] : 256 blocks x 16KB
    float4_t z4 = {0.f, 0.f, 0.f, 0.f};
    float4_t* o = (float4_t*)(out + ((size_t)(blockIdx.y * 16 + blockIdx.x)) * 4096);
    #pragma unroll
    for (int i = 0; i < 4; ++i) o[i * 256 + tid] = z4;
    return;
  }

  // z == 24: router, 4 tokens per block (one wave each)
  const int wid  = tid >> 6;
  const int lane = tid & 63;
  const int t = (blockIdx.y * 16 + blockIdx.x) * 4 + wid;
  const float* xr = x + (size_t)t * D_DIM;
  float acc[E_EXP];
  #pragma unroll
  for (int e = 0; e < E_EXP; ++e) acc[e] = 0.f;
  for (int d = lane; d < D_DIM; d += 64) {
    float xv = xr[d];
    float4_t g0 = *(const float4_t*)(gw + d * E_EXP);
    float4_t g1 = *(const float4_t*)(gw + d * E_EXP + 4);
    acc[0] += xv * g0[0]; acc[1] += xv * g0[1];
    acc[2] += xv * g0[2]; acc[3] += xv * g0[3];
    acc[4] += xv * g1[0]; acc[5] += xv * g1[1];
    acc[6] += xv * g1[2]; acc[7] += xv * g1[3];
  }
  #pragma unroll
  for (int off = 32; off >= 1; off >>= 1) {
    #pragma unroll
    for (int e = 0; e < E_EXP; ++e) acc[e] += __shfl_down(acc[e], off, 64);
  }
  if (lane == 0) {
    float m = acc[0];
    #pragma unroll
    for (int e = 1; e < E_EXP; ++e) m = fmaxf(m, acc[e]);
    float p[E_EXP]; float s = 0.f;
    #pragma unroll
    for (int e = 0; e < E_EXP; ++e) { p[e] = __expf(acc[e] - m); s += p[e]; }
    float inv = 1.f / s;
    #pragma unroll
    for (int e = 0; e < E_EXP; ++e) p[e] *= inv;
    int i1 = 0;
    #pragma unroll
    for (int e = 1; e < E_EXP; ++e) if (p[e] > p[i1]) i1 = e;  // jax low-index tiebreak
    int i2 = (i1 == 0) ? 1 : 0;
    #pragma unroll
    for (int e = 0; e < E_EXP; ++e) {
      if (e == i1 || e == i2) continue;
      if (p[e] > p[i2]) i2 = e;
    }
    idx2[2 * t]     = i1;  scale2[2 * t]     = p[i1];
    idx2[2 * t + 1] = i2;  scale2[2 * t + 1] = p[i2];
  }
}

// In-block routing scan (replaces the serial 1-block scan kernel):
// deterministic pair assignment p = base[e] + rank of (t,s) among expert-e
// pairs in j=2t+s order. Histogram -> 64-aligned bases -> chunk-prefix rank.
// ~1-2us of LDS/VALU per block, fully parallel across the grid.
#define SCAN_DECLS                                                            \
  __shared__ unsigned char sE[2048];                                          \
  __shared__ unsigned char sLC[8 * 256];                                      \
  __shared__ int scnt[8];                                                     \
  __shared__ int spref[256];                                                  \
  __shared__ int stok[64];                                                    \
  __shared__ float ssc[64];

#define SCAN_BODY(idx2_, scale2_, mt_, tid_, E_OUT, ROW0_OUT)                 \
  {                                                                           \
    uint4_t a4 = *(const uint4_t*)((idx2_) + (tid_) * 8);                     \
    uint4_t b4 = *(const uint4_t*)((idx2_) + (tid_) * 8 + 4);                 \
    unsigned char lc[8] = {0, 0, 0, 0, 0, 0, 0, 0};                           \
    int ev[8] = {(int)a4[0], (int)a4[1], (int)a4[2], (int)a4[3],              \
                 (int)b4[0], (int)b4[1], (int)b4[2], (int)b4[3]};             \
    _Pragma("unroll")                                                         \
    for (int i = 0; i < 8; ++i) {                                             \
      int ee = ev[i]; lc[ee]++; sE[(tid_) * 8 + i] = (unsigned char)ee;       \
    }                                                                         \
    _Pragma("unroll")                                                         \
    for (int ee = 0; ee < 8; ++ee) sLC[ee * 256 + (tid_)] = lc[ee];           \
  }                                                                           \
  __syncthreads();                                                            \
  if ((tid_) < 8) {                                                           \
    int s = 0; const unsigned char* pp = &sLC[(tid_) * 256];                  \
    for (int j = 0; j < 256; ++j) s += pp[j];                                 \
    scnt[(tid_)] = s;                                                         \
  }                                                                           \
  __syncthreads();                                                            \
  int E_OUT = -1, ROW0_OUT = 0, mloc_ = 0, nmt_ = 0;                          \
  {                                                                           \
    int b = 0, ts = 0;                                                        \
    _Pragma("unroll")                                                         \
    for (int ee = 0; ee < 8; ++ee) {                                          \
      int c = scnt[ee]; int nt = (c + 63) >> 6;                               \
      if (E_OUT < 0 && (mt_) < ts + nt) {                                     \
        E_OUT = ee; mloc_ = (mt_) - ts; ROW0_OUT = b + mloc_ * 64;            \
      }                                                                       \
      ts += nt; b += nt * 64;                                                 \
    }                                                                         \
    nmt_ = ts;                                                                \
  }                                                                           \
  if ((mt_) >= nmt_) return;                                                  \
  const int cnt_e_ = scnt[E_OUT];                                             \
  spref[(tid_)] = sLC[E_OUT * 256 + (tid_)];                                  \
  __syncthreads();                                                            \
  for (int off = 1; off < 256; off <<= 1) {                                   \
    int v = ((tid_) >= off) ? spref[(tid_) - off] : 0;                        \
    __syncthreads();                                                          \
    spref[(tid_)] += v;                                                       \
    __syncthreads();                                                          \
  }                                                                           \
  if ((tid_) < 64) {                                                          \
    int R = mloc_ * 64 + (tid_);                                              \
    int tok = -1; float sc = 0.f;                                             \
    if (R < cnt_e_) {                                                         \
      int c = 0;                                                              \
      while (spref[c] <= R) ++c;                                              \
      int need = R - (c ? spref[c - 1] : 0);                                  \
      for (int i = 0; i < 8; ++i) {                                           \
        if (sE[c * 8 + i] == (unsigned char)E_OUT) {                          \
          if (need == 0) { int j = c * 8 + i; tok = j >> 1;                   \
                           sc = (scale2_) ? (scale2_)[j] : 0.f; break; }      \
          --need;                                                             \
        }                                                                     \
      }                                                                       \
    }                                                                         \
    stok[(tid_)] = tok; ssc[(tid_)] = sc;                                     \
  }                                                                           \
  __syncthreads();

// ------- gemm1: h[p][H] = silu((s*x)@w1e) * ((s*x)@w3e); 64m x 32n ---------
__global__ __launch_bounds__(256, 4) void gemm1_kernel(
    const float* __restrict__ x, const short* __restrict__ w13t,
    const int* __restrict__ idx2, const float* __restrict__ scale2,
    short* __restrict__ h) {
  __shared__ short As[64 * LDA];    // 9.2 KB
  __shared__ short B1s[32 * LDA];   // 4.6 KB
  __shared__ short B3s[32 * LDA];   // 4.6 KB
  SCAN_DECLS
  const int mt  = blockIdx.y;
  const int tid = threadIdx.x;
  SCAN_BODY(idx2, scale2, mt, tid, e, row0)

  const int n0   = blockIdx.x * 32;
  const int lane = tid & 63, wid = tid >> 6;
  const int wr = wid >> 1, wc = wid & 1;
  const int q = lane >> 4, ln = lane & 15;
  const short* bsrc = w13t + (size_t)e * D_DIM * (2 * H_DIM);

  // A staging: thread owns one 16-float k-segment of one row (gather + scale)
  const int ar = tid >> 2, ak = (tid & 3) * 16;
  const int   tokr = stok[ar];
  const float sc   = ssc[ar];                   // 0 for pad rows -> zeros
  const float* xrow = x + (size_t)(tokr < 0 ? 0 : tokr) * D_DIM + ak;
  // B staging: thread owns one 8-short k-unit of one row
  const int br = tid >> 3, bu = (tid & 7) * 8;
  const short* b1p = bsrc + (size_t)(n0 + br) * D_DIM + bu;
  const short* b3p = bsrc + (size_t)(H_DIM + n0 + br) * D_DIM + bu;

  float4_t acc1[2], acc3[2];
  acc1[0] = acc1[1] = acc3[0] = acc3[1] = (float4_t){0.f, 0.f, 0.f, 0.f};

  for (int k0 = 0; k0 < D_DIM; k0 += 64) {
    float4_t v0 = *(const float4_t*)(xrow + k0);
    float4_t v1 = *(const float4_t*)(xrow + k0 + 4);
    float4_t v2 = *(const float4_t*)(xrow + k0 + 8);
    float4_t v3 = *(const float4_t*)(xrow + k0 + 12);
    uint4_t vb1 = *(const uint4_t*)(b1p + k0);
    uint4_t vb3 = *(const uint4_t*)(b3p + k0);
    uint4_t u0 = {pkbf(v0[0] * sc, v0[1] * sc), pkbf(v0[2] * sc, v0[3] * sc),
                  pkbf(v1[0] * sc, v1[1] * sc), pkbf(v1[2] * sc, v1[3] * sc)};
    uint4_t u1 = {pkbf(v2[0] * sc, v2[1] * sc), pkbf(v2[2] * sc, v2[3] * sc),
                  pkbf(v3[0] * sc, v3[1] * sc), pkbf(v3[2] * sc, v3[3] * sc)};
    *(uint4_t*)&As[ar * LDA + ak]     = u0;
    *(uint4_t*)&As[ar * LDA + ak + 8] = u1;
    *(uint4_t*)&B1s[br * LDA + bu] = vb1;
    *(uint4_t*)&B3s[br * LDA + bu] = vb3;
    __syncthreads();

    short8_t af[2][2], b1f[2], b3f[2];
    #pragma unroll
    for (int i = 0; i < 2; ++i)
      #pragma unroll
      for (int kk = 0; kk < 2; ++kk)
        af[i][kk] = *(const short8_t*)&As[(wr * 32 + i * 16 + ln) * LDA + kk * 32 + q * 8];
    #pragma unroll
    for (int kk = 0; kk < 2; ++kk) {
      b1f[kk] = *(const short8_t*)&B1s[(wc * 16 + ln) * LDA + kk * 32 + q * 8];
      b3f[kk] = *(const short8_t*)&B3s[(wc * 16 + ln) * LDA + kk * 32 + q * 8];
    }
    #pragma unroll
    for (int i = 0; i < 2; ++i)
      #pragma unroll
      for (int kk = 0; kk < 2; ++kk) {
        acc1[i] = __builtin_amdgcn_mfma_f32_16x16x32_bf16(af[i][kk], b1f[kk], acc1[i], 0, 0, 0);
        acc3[i] = __builtin_amdgcn_mfma_f32_16x16x32_bf16(af[i][kk], b3f[kk], acc3[i], 0, 0, 0);
      }
    __syncthreads();
  }

  #pragma unroll
  for (int i = 0; i < 2; ++i) {
    int r_base = row0 + wr * 32 + i * 16 + q * 4;
    int col = n0 + wc * 16 + ln;
    #pragma unroll
    for (int rr = 0; rr < 4; ++rr) {
      float c1 = acc1[i][rr];
      float c3 = acc3[i][rr];
      float sig = 1.f / (1.f + __expf(-c1));
      h[(size_t)(r_base + rr) * H_DIM + col] = f2bf(c1 * sig * c3);
    }
  }
}

// -- gemm2 (fused combine): out[tok] += h[p][H] @ w2t[e]; 64x64 tiles --------
__global__ __launch_bounds__(256, 4) void gemm2_kernel(
    const short* __restrict__ h, const short* __restrict__ w2t,
    const int* __restrict__ idx2, float* __restrict__ out) {
  __shared__ short As[64 * LDA];   // 9.2 KB
  __shared__ short Bs[64 * LDA];   // 9.2 KB
  SCAN_DECLS
  const int mt  = blockIdx.y;
  const int tid = threadIdx.x;
  SCAN_BODY(idx2, (const float*)nullptr, mt, tid, e, row0)

  const int n0   = blockIdx.x * 64;
  const int lane = tid & 63, wid = tid >> 6;
  const int wr = wid >> 1, wc = wid & 1;
  const int q = lane >> 4, ln = lane & 15;
  const short* bsrc = w2t + (size_t)e * D_DIM * H_DIM;  // [1024 n][512 k]

  const int ar = tid >> 2, ak = (tid & 3) * 16;
  const short* arow = h + (size_t)(row0 + ar) * H_DIM + ak;
  const short* brow = bsrc + (size_t)(n0 + ar) * H_DIM + ak;

  float4_t acc[2][2];
  #pragma unroll
  for (int i = 0; i < 2; ++i)
    #pragma unroll
    for (int j = 0; j < 2; ++j) acc[i][j] = (float4_t){0.f, 0.f, 0.f, 0.f};

  for (int k0 = 0; k0 < H_DIM; k0 += 64) {
    uint4_t va0 = *(const uint4_t*)(arow + k0);
    uint4_t va1 = *(const uint4_t*)(arow + k0 + 8);
    uint4_t vb0 = *(const uint4_t*)(brow + k0);
    uint4_t vb1 = *(const uint4_t*)(brow + k0 + 8);
    *(uint4_t*)&As[ar * LDA + ak]     = va0;
    *(uint4_t*)&As[ar * LDA + ak + 8] = va1;
    *(uint4_t*)&Bs[ar * LDA + ak]     = vb0;
    *(uint4_t*)&Bs[ar * LDA + ak + 8] = vb1;
    __syncthreads();

    short8_t af[2][2], bf[2][2];
    #pragma unroll
    for (int i = 0; i < 2; ++i)
      #pragma unroll
      for (int kk = 0; kk < 2; ++kk) {
        af[i][kk] = *(const short8_t*)&As[(wr * 32 + i * 16 + ln) * LDA + kk * 32 + q * 8];
        bf[i][kk] = *(const short8_t*)&Bs[(wc * 32 + i * 16 + ln) * LDA + kk * 32 + q * 8];
      }
    #pragma unroll
    for (int i = 0; i < 2; ++i)
      #pragma unroll
      for (int j = 0; j < 2; ++j)
        #pragma unroll
        for (int kk = 0; kk < 2; ++kk)
          acc[i][j] = __builtin_amdgcn_mfma_f32_16x16x32_bf16(af[i][kk], bf[j][kk], acc[i][j], 0, 0, 0);
    __syncthreads();
  }

  // ---- epilogue: scatter-add into out[tok]; skip pad rows (tok < 0)
  #pragma unroll
  for (int i = 0; i < 2; ++i) {
    int r_local = wr * 32 + i * 16 + q * 4;
    #pragma unroll
    for (int rr = 0; rr < 4; ++rr) {
      int tok = stok[r_local + rr];
      if (tok < 0) continue;
      float* orow = out + (size_t)tok * D_DIM;
      #pragma unroll
      for (int j = 0; j < 2; ++j) {
        int col = n0 + wc * 32 + j * 16 + ln;
        atomicAdd(orow + col, acc[i][j][rr]);
      }
    }
  }
}

extern "C" void kernel_launch(void* const* d_in, const int* in_sizes, int n_in,
                              void* d_out, int out_size, void* d_ws, size_t ws_size,
                              hipStream_t stream) {
  const float* x  = (const float*)d_in[0];   // [2,512,1024]
  const float* gw = (const float*)d_in[1];   // [1024,8]
  const float* w1 = (const float*)d_in[2];   // [8,1024,512] gate
  const float* w2 = (const float*)d_in[3];   // [8,512,1024] down
  const float* w3 = (const float*)d_in[4];   // [8,1024,512] up
  float* out = (float*)d_out;

  char* ws = (char*)d_ws;
  int*   idx2    = (int*)  (ws);                       // 8KB
  float* scale2  = (float*)(ws + 8192);                // 8KB
  short* h       = (short*)(ws + (1u << 20));          // 2.62 MB
  short* w13t    = (short*)(ws + (4u << 20));          // 16.8 MB
  short* w2t     = (short*)(ws + (21u << 20));         // 8.4 MB

  // prep: all weight conv planes + router + out zeroing in one launch
  prep_kernel<<<dim3(16, 16, 26), dim3(256), 0, stream>>>(
      w1, w3, w2, x, gw, w13t, w2t, idx2, scale2, out);
  gemm1_kernel<<<dim3(H_DIM / 32, MAX_MT), dim3(256), 0, stream>>>(
      x, w13t, idx2, scale2, h);
  gemm2_kernel<<<dim3(D_DIM / 64, MAX_MT), dim3(256), 0, stream>>>(
      h, w2t, idx2, out);
}

// Round 9
// 146.941 us; speedup vs baseline: 2.8364x; 1.1293x over previous
//
#include <hip/hip_runtime.h>
#include <hip/hip_bf16.h>
#include <cstddef>

#define T_TOK 1024
#define D_DIM 1024
#define H_DIM 512
#define E_EXP 8
#define P_CAP 2560          // max padded pairs: 2048 + 8*31 = 2296 -> 2560
#define MAX_MT 72           // 32-row m-tiles: <= 2296/32 = 71.75 -> 72 slots
#define LDA 72              // shorts per LDS row: 64 data + 8 pad (144B, 16B-aligned)

typedef __attribute__((ext_vector_type(4))) float    float4_t;
typedef __attribute__((ext_vector_type(8))) short    short8_t;
typedef __attribute__((ext_vector_type(4))) unsigned uint4_t;

__device__ __forceinline__ short f2bf(float f) {
  union { float f; unsigned u; } v; v.f = f;
  unsigned u = v.u;
  u += 0x7FFFu + ((u >> 16) & 1u);
  return (short)(u >> 16);
}

// packed fp32x2 -> bf16x2; low short = a, high = b
__device__ __forceinline__ unsigned pkbf(float a, float b) {
  union { __hip_bfloat162 h; unsigned u; } v;
  v.h = __float22bfloat162_rn(make_float2(a, b));
  return v.u;
}

// ---- prep: weight transpose+convert (z<24) + router (z==24) + out=0 (z==25)
// tile stride 69 floats (odd) keeps transpose reads <=2-way (free; r7 PMC
// showed 4.5M conflicts from the old stride-68 8-way pattern).
__global__ __launch_bounds__(256) void prep_kernel(
    const float* __restrict__ w1, const float* __restrict__ w3,
    const float* __restrict__ w2, const float* __restrict__ x,
    const float* __restrict__ gw, short* __restrict__ w13t,
    short* __restrict__ w2t, int* __restrict__ idx2,
    float* __restrict__ scale2, float* __restrict__ out) {
  __shared__ float tile[64][69];
  const int z = blockIdx.z;
  const int tid = threadIdx.x;

  if (z < 24) {
    const float* src; short* dst; int N, ldd, row_off;
    if (z < 16) {
      if (blockIdx.y >= 8) return;          // N=512 -> 8 n-tiles
      int which = z >> 3, e = z & 7;
      src = (which ? w3 : w1) + (size_t)e * D_DIM * H_DIM;
      dst = w13t + (size_t)e * D_DIM * (2 * H_DIM);
      N = H_DIM; ldd = D_DIM; row_off = which ? H_DIM : 0;
    } else {
      if (blockIdx.x >= 8) return;          // K=512 -> 8 k-tiles
      int e = z - 16;
      src = w2 + (size_t)e * H_DIM * D_DIM;
      dst = w2t + (size_t)e * D_DIM * H_DIM;
      N = D_DIM; ldd = H_DIM; row_off = 0;
    }
    const int k0 = blockIdx.x * 64, n0 = blockIdx.y * 64;
    const int kr = tid >> 4, nc = (tid & 15) * 4;
    #pragma unroll
    for (int p = 0; p < 4; ++p) {
      int k = p * 16 + kr;
      float4_t v = *(const float4_t*)(src + (size_t)(k0 + k) * N + n0 + nc);
      tile[k][nc]     = v[0];
      tile[k][nc + 1] = v[1];
      tile[k][nc + 2] = v[2];
      tile[k][nc + 3] = v[3];
    }
    __syncthreads();
    const int r8 = tid >> 3, c8 = tid & 7;
    #pragma unroll
    for (int p = 0; p < 2; ++p) {
      int row = p * 32 + r8;
      uint4_t u;
      #pragma unroll
      for (int jj = 0; jj < 4; ++jj)
        u[jj] = pkbf(tile[c8 * 8 + 2 * jj][row], tile[c8 * 8 + 2 * jj + 1][row]);
      *(uint4_t*)(dst + (size_t)(row_off + n0 + row) * ldd + k0 + c8 * 8) = u;
    }
    return;
  }

  if (z == 25) {                            // zero out[] : 256 blocks x 16KB
    float4_t z4 = {0.f, 0.f, 0.f, 0.f};
    float4_t* o = (float4_t*)(out + ((size_t)(blockIdx.y * 16 + blockIdx.x)) * 4096);
    #pragma unroll
    for (int i = 0; i < 4; ++i) o[i * 256 + tid] = z4;
    return;
  }

  // z == 24: router, 4 tokens per block (one wave each)
  const int wid  = tid >> 6;
  const int lane = tid & 63;
  const int t = (blockIdx.y * 16 + blockIdx.x) * 4 + wid;
  const float* xr = x + (size_t)t * D_DIM;
  float acc[E_EXP];
  #pragma unroll
  for (int e = 0; e < E_EXP; ++e) acc[e] = 0.f;
  for (int d = lane; d < D_DIM; d += 64) {
    float xv = xr[d];
    float4_t g0 = *(const float4_t*)(gw + d * E_EXP);
    float4_t g1 = *(const float4_t*)(gw + d * E_EXP + 4);
    acc[0] += xv * g0[0]; acc[1] += xv * g0[1];
    acc[2] += xv * g0[2]; acc[3] += xv * g0[3];
    acc[4] += xv * g1[0]; acc[5] += xv * g1[1];
    acc[6] += xv * g1[2]; acc[7] += xv * g1[3];
  }
  #pragma unroll
  for (int off = 32; off >= 1; off >>= 1) {
    #pragma unroll
    for (int e = 0; e < E_EXP; ++e) acc[e] += __shfl_down(acc[e], off, 64);
  }
  if (lane == 0) {
    float m = acc[0];
    #pragma unroll
    for (int e = 1; e < E_EXP; ++e) m = fmaxf(m, acc[e]);
    float p[E_EXP]; float s = 0.f;
    #pragma unroll
    for (int e = 0; e < E_EXP; ++e) { p[e] = __expf(acc[e] - m); s += p[e]; }
    float inv = 1.f / s;
    #pragma unroll
    for (int e = 0; e < E_EXP; ++e) p[e] *= inv;
    int i1 = 0;
    #pragma unroll
    for (int e = 1; e < E_EXP; ++e) if (p[e] > p[i1]) i1 = e;  // jax low-index tiebreak
    int i2 = (i1 == 0) ? 1 : 0;
    #pragma unroll
    for (int e = 0; e < E_EXP; ++e) {
      if (e == i1 || e == i2) continue;
      if (p[e] > p[i2]) i2 = e;
    }
    idx2[2 * t]     = i1;  scale2[2 * t]     = p[i1];
    idx2[2 * t + 1] = i2;  scale2[2 * t + 1] = p[i2];
  }
}

// ---- scan/assign: histogram -> 32-aligned bases -> tile table -> pair lists
__global__ __launch_bounds__(256) void scan_kernel(
    const int* __restrict__ idx2, const float* __restrict__ scale2,
    int* __restrict__ pair_tok, float* __restrict__ pair_scale,
    int* __restrict__ meta) {
  __shared__ int cnt[E_EXP], base[E_EXP], cur[E_EXP];
  const int tid = threadIdx.x;
  if (tid < E_EXP) { cnt[tid] = 0; cur[tid] = 0; }
  for (int p = tid; p < P_CAP; p += 256) { pair_tok[p] = -1; pair_scale[p] = 0.f; }
  __syncthreads();
  for (int t = tid; t < T_TOK; t += 256) {
    atomicAdd(&cnt[idx2[2 * t]], 1);
    atomicAdd(&cnt[idx2[2 * t + 1]], 1);
  }
  __syncthreads();
  if (tid == 0) {
    int b = 0, g = 0;
    for (int e = 0; e < E_EXP; ++e) {
      base[e] = b;
      int al = (cnt[e] + 31) & ~31;       // 32-row tiles
      for (int j = 0; j < al; j += 32) { meta[1 + g] = e; meta[81 + g] = b + j; ++g; }
      b += al;
    }
    meta[0] = g;  // n_mtiles (<= 72)
  }
  __syncthreads();
  for (int t = tid; t < T_TOK; t += 256) {
    #pragma unroll
    for (int s = 0; s < 2; ++s) {
      int e = idx2[2 * t + s];
      int p = base[e] + atomicAdd(&cur[e], 1);
      pair_tok[p] = t;
      pair_scale[p] = scale2[2 * t + s];
    }
  }
}

// ------- gemm1: h[p][H] = silu((s*x)@w1e) * ((s*x)@w3e); 32m x 32n ---------
// Half-size m-tiles: ~1120 blocks (4.5/CU) for TLP latency hiding.
__global__ __launch_bounds__(256, 6) void gemm1_kernel(
    const float* __restrict__ x, const short* __restrict__ w13t,
    const int* __restrict__ pair_tok, const float* __restrict__ pair_scale,
    const int* __restrict__ meta, short* __restrict__ h) {
  __shared__ short As[32 * LDA];    // 4.6 KB
  __shared__ short B1s[32 * LDA];   // 4.6 KB
  __shared__ short B3s[32 * LDA];   // 4.6 KB
  const int mt = blockIdx.y;
  if (mt >= meta[0]) return;
  const int e    = meta[1 + mt];
  const int row0 = meta[81 + mt];
  const int n0   = blockIdx.x * 32;
  const int tid = threadIdx.x, lane = tid & 63, wid = tid >> 6;
  const int wr = wid >> 1, wc = wid & 1;        // 2x2 waves, each 16m x 16n
  const int q = lane >> 4, ln = lane & 15;
  const short* bsrc = w13t + (size_t)e * D_DIM * (2 * H_DIM);

  // A staging: thread owns one 8-float k-segment of one row (gather + scale)
  const int ar = tid >> 3, ak = (tid & 7) * 8;
  const int   tokr = pair_tok[row0 + ar];
  const float sc   = pair_scale[row0 + ar];     // 0 for pad rows -> zeros
  const float* xrow = x + (size_t)(tokr < 0 ? 0 : tokr) * D_DIM + ak;
  // B staging: thread owns one 8-short k-unit of one row
  const int br = tid >> 3, bu = (tid & 7) * 8;
  const short* b1p = bsrc + (size_t)(n0 + br) * D_DIM + bu;
  const short* b3p = bsrc + (size_t)(H_DIM + n0 + br) * D_DIM + bu;

  float4_t acc1 = {0.f, 0.f, 0.f, 0.f}, acc3 = {0.f, 0.f, 0.f, 0.f};

  for (int k0 = 0; k0 < D_DIM; k0 += 64) {
    float4_t v0 = *(const float4_t*)(xrow + k0);
    float4_t v1 = *(const float4_t*)(xrow + k0 + 4);
    uint4_t vb1 = *(const uint4_t*)(b1p + k0);
    uint4_t vb3 = *(const uint4_t*)(b3p + k0);
    uint4_t u0 = {pkbf(v0[0] * sc, v0[1] * sc), pkbf(v0[2] * sc, v0[3] * sc),
                  pkbf(v1[0] * sc, v1[1] * sc), pkbf(v1[2] * sc, v1[3] * sc)};
    *(uint4_t*)&As[ar * LDA + ak]  = u0;
    *(uint4_t*)&B1s[br * LDA + bu] = vb1;
    *(uint4_t*)&B3s[br * LDA + bu] = vb3;
    __syncthreads();

    short8_t af[2], b1f[2], b3f[2];
    #pragma unroll
    for (int kk = 0; kk < 2; ++kk) {
      af[kk]  = *(const short8_t*)&As[(wr * 16 + ln) * LDA + kk * 32 + q * 8];
      b1f[kk] = *(const short8_t*)&B1s[(wc * 16 + ln) * LDA + kk * 32 + q * 8];
      b3f[kk] = *(const short8_t*)&B3s[(wc * 16 + ln) * LDA + kk * 32 + q * 8];
    }
    #pragma unroll
    for (int kk = 0; kk < 2; ++kk) {
      acc1 = __builtin_amdgcn_mfma_f32_16x16x32_bf16(af[kk], b1f[kk], acc1, 0, 0, 0);
      acc3 = __builtin_amdgcn_mfma_f32_16x16x32_bf16(af[kk], b3f[kk], acc3, 0, 0, 0);
    }
    __syncthreads();
  }

  {
    int r_base = row0 + wr * 16 + q * 4;
    int col = n0 + wc * 16 + ln;
    #pragma unroll
    for (int rr = 0; rr < 4; ++rr) {
      float c1 = acc1[rr];
      float c3 = acc3[rr];
      float sig = 1.f / (1.f + __expf(-c1));
      h[(size_t)(r_base + rr) * H_DIM + col] = f2bf(c1 * sig * c3);
    }
  }
}

// -- gemm2 (fused combine): out[tok] += h[p][H] @ w2t[e]; 32m x 64n ----------
__global__ __launch_bounds__(256, 6) void gemm2_kernel(
    const short* __restrict__ h, const short* __restrict__ w2t,
    const int* __restrict__ pair_tok, const int* __restrict__ meta,
    float* __restrict__ out) {
  __shared__ short As[32 * LDA];   // 4.6 KB
  __shared__ short Bs[64 * LDA];   // 9.2 KB
  const int mt = blockIdx.y;
  if (mt >= meta[0]) return;
  const int e    = meta[1 + mt];
  const int row0 = meta[81 + mt];
  const int n0   = blockIdx.x * 64;
  const int tid = threadIdx.x, lane = tid & 63, wid = tid >> 6;
  const int wr = wid >> 1, wc = wid & 1;        // 2x2 waves, each 16m x 32n
  const int q = lane >> 4, ln = lane & 15;
  const short* bsrc = w2t + (size_t)e * D_DIM * H_DIM;  // [1024 n][512 k]

  const int ar = tid >> 3, ak = (tid & 7) * 8;
  const short* arow = h + (size_t)(row0 + ar) * H_DIM + ak;
  const int br = tid >> 2, bk = (tid & 3) * 16;
  const short* brow = bsrc + (size_t)(n0 + br) * H_DIM + bk;

  float4_t acc[2];
  acc[0] = acc[1] = (float4_t){0.f, 0.f, 0.f, 0.f};

  for (int k0 = 0; k0 < H_DIM; k0 += 64) {
    uint4_t va  = *(const uint4_t*)(arow + k0);
    uint4_t vb0 = *(const uint4_t*)(brow + k0);
    uint4_t vb1 = *(const uint4_t*)(brow + k0 + 8);
    *(uint4_t*)&As[ar * LDA + ak]     = va;
    *(uint4_t*)&Bs[br * LDA + bk]     = vb0;
    *(uint4_t*)&Bs[br * LDA + bk + 8] = vb1;
    __syncthreads();

    short8_t af[2], bf[2][2];
    #pragma unroll
    for (int kk = 0; kk < 2; ++kk) {
      af[kk] = *(const short8_t*)&As[(wr * 16 + ln) * LDA + kk * 32 + q * 8];
      #pragma unroll
      for (int j = 0; j < 2; ++j)
        bf[j][kk] = *(const short8_t*)&Bs[(wc * 32 + j * 16 + ln) * LDA + kk * 32 + q * 8];
    }
    #pragma unroll
    for (int j = 0; j < 2; ++j)
      #pragma unroll
      for (int kk = 0; kk < 2; ++kk)
        acc[j] = __builtin_amdgcn_mfma_f32_16x16x32_bf16(af[kk], bf[j][kk], acc[j], 0, 0, 0);
    __syncthreads();
  }

  // ---- epilogue: scatter-add into out[tok]; skip pad rows (tok < 0)
  {
    int r_base = row0 + wr * 16 + q * 4;
    #pragma unroll
    for (int rr = 0; rr < 4; ++rr) {
      int tok = pair_tok[r_base + rr];
      if (tok < 0) continue;
      float* orow = out + (size_t)tok * D_DIM;
      #pragma unroll
      for (int j = 0; j < 2; ++j) {
        int col = n0 + wc * 32 + j * 16 + ln;
        atomicAdd(orow + col, acc[j][rr]);
      }
    }
  }
}

extern "C" void kernel_launch(void* const* d_in, const int* in_sizes, int n_in,
                              void* d_out, int out_size, void* d_ws, size_t ws_size,
                              hipStream_t stream) {
  const float* x  = (const float*)d_in[0];   // [2,512,1024]
  const float* gw = (const float*)d_in[1];   // [1024,8]
  const float* w1 = (const float*)d_in[2];   // [8,1024,512] gate
  const float* w2 = (const float*)d_in[3];   // [8,512,1024] down
  const float* w3 = (const float*)d_in[4];   // [8,1024,512] up
  float* out = (float*)d_out;

  char* ws = (char*)d_ws;
  int*   idx2    = (int*)  (ws);                       // 8KB
  float* scale2  = (float*)(ws + 8192);                // 8KB
  int*   ptok    = (int*)  (ws + 16384);               // 10KB (16KB slot)
  float* pscale  = (float*)(ws + 32768);               // 10KB (16KB slot)
  int*   meta    = (int*)  (ws + 49152);               // 640B (16KB slot)
  short* h       = (short*)(ws + (1u << 20));          // 2.62 MB
  short* w13t    = (short*)(ws + (4u << 20));          // 16.8 MB
  short* w2t     = (short*)(ws + (21u << 20));         // 8.4 MB

  prep_kernel<<<dim3(16, 16, 26), dim3(256), 0, stream>>>(
      w1, w3, w2, x, gw, w13t, w2t, idx2, scale2, out);
  scan_kernel<<<dim3(1), dim3(256), 0, stream>>>(idx2, scale2, ptok, pscale, meta);
  gemm1_kernel<<<dim3(H_DIM / 32, MAX_MT), dim3(256), 0, stream>>>(
      x, w13t, ptok, pscale, meta, h);
  gemm2_kernel<<<dim3(D_DIM / 64, MAX_MT), dim3(256), 0, stream>>>(
      h, w2t, ptok, meta, out);
}